// Round 9
// baseline (136.816 us; speedup 1.0000x reference)
//
#include <hip/hip_runtime.h>
#include <hip/hip_fp16.h>
#include <math.h>
#include <stdint.h>

namespace {

constexpr int Bsz   = 16384;
constexpr int T     = 200;
constexpr int F     = 4;
constexpr int H     = 10;
constexpr int HP    = 16;   // FC LDS padding: 16 slots/step
constexpr int BLOCK = 256;

// tanh(x) = 1 - 2/(exp(2x)+1); saturates correctly to +/-1 for |x| large.
__device__ __forceinline__ float fast_tanh(float x) {
  float e = exp2f(x * 2.8853900817779268f);   // exp(2x) via v_exp_f32
  return 1.0f - 2.0f * __builtin_amdgcn_rcpf(e + 1.0f);
}

__device__ __forceinline__ float fast_sigmoid(float x) {
  float e = exp2f(x * -1.4426950408889634f);  // exp(-x)
  return __builtin_amdgcn_rcpf(1.0f + e);
}

// DPP quad_perm [1,0,3,2]: swap adjacent lanes within each quad (pair swap).
__device__ __forceinline__ float pairswap(float v) {
  return __int_as_float(__builtin_amdgcn_mov_dpp(
      __float_as_int(v), 0xB1, 0xF, 0xF, true));
}

// ds_swizzle BitMode broadcast within each 16-lane group:
// new_lane = (lane & 0x10) | SRC  (SRC = source sub-lane, even, 0..8)
template <int SRC>
__device__ __forceinline__ uint32_t swz16(uint32_t v) {
  return (uint32_t)__builtin_amdgcn_ds_swizzle((int)v, (SRC << 5) | 0x10);
}

#define PIN(v) asm volatile("" : "+v"(v))

// v_fma_mix_f32 with BOTH operands f16-packed: s += w.half * h.half (f32 acc)
__device__ __forceinline__ void mix2_lo(float& s, uint32_t wpk, uint32_t hpk) {
  asm("v_fma_mix_f32 %0, %1, %2, %0 op_sel_hi:[1,1,0]"
      : "+v"(s) : "v"(wpk), "v"(hpk));
}
__device__ __forceinline__ void mix2_hi(float& s, uint32_t wpk, uint32_t hpk) {
  asm("v_fma_mix_f32 %0, %1, %2, %0 op_sel:[1,1,0] op_sel_hi:[1,1,0]"
      : "+v"(s) : "v"(wpk), "v"(hpk));
}

// pack two f32 -> f16x2 (RNE, init-time only)
__device__ __forceinline__ uint32_t pkh(float a, float b) {
  return (uint32_t)__half_as_ushort(__float2half(a)) |
         ((uint32_t)__half_as_ushort(__float2half(b)) << 16);
}
// pack two f32 -> f16x2 (RTZ, one v_cvt_pkrtz)
__device__ __forceinline__ uint32_t pkrtz(float a, float b) {
  auto p = __builtin_amdgcn_cvt_pkrtz(a, b);
  return __builtin_bit_cast(uint32_t, p);
}

// 16-lane-per-element split: 1 hidden unit per lane, everything f16-packed.
// Live set ~55 regs (19 packed weights + 10 packed h + temps) — below every
// arch-VGPR allocation the compiler has ever granted this kernel (48-204),
// so in-loop register shuffling/spilling is impossible by construction.
// 4096 waves = 4 waves/SIMD for latency hiding.
__global__ __launch_bounds__(BLOCK)
__attribute__((amdgpu_waves_per_eu(4, 4)))
void rnn2_hex(
    const float* __restrict__ x,
    const float* __restrict__ W_ih0, const float* __restrict__ W_hh0,
    const float* __restrict__ b_ih0, const float* __restrict__ b_hh0,
    const float* __restrict__ W_ih1, const float* __restrict__ W_hh1,
    const float* __restrict__ b_ih1, const float* __restrict__ b_hh1,
    const float* __restrict__ W_fc, const float* __restrict__ b_fc,
    float* __restrict__ out) {
  __shared__ float s_wfc[T * HP];
  for (int i = threadIdx.x; i < T * HP; i += BLOCK) {
    int t = i >> 4, u = i & 15;
    s_wfc[i] = (u < H) ? W_fc[t * H + u] : 0.0f;
  }
  __syncthreads();

  const int g = blockIdx.x * BLOCK + threadIdx.x;
  const int e = g >> 4;            // batch element
  const int r = g & 15;            // unit index (real for r < 10)
  const bool valid = (r < H);

  // ---- my unit's weights as f16 pairs ----
  uint32_t wh0p[5], wi1p[5], wh1p[5], wi0p[2];
#pragma unroll
  for (int k = 0; k < 5; ++k) {
    wh0p[k] = valid ? pkh(W_hh0[r * H + 2 * k], W_hh0[r * H + 2 * k + 1]) : 0u;
    wi1p[k] = valid ? pkh(W_ih1[r * H + 2 * k], W_ih1[r * H + 2 * k + 1]) : 0u;
    wh1p[k] = valid ? pkh(W_hh1[r * H + 2 * k], W_hh1[r * H + 2 * k + 1]) : 0u;
  }
  wi0p[0] = valid ? pkh(W_ih0[r * F + 0], W_ih0[r * F + 1]) : 0u;
  wi0p[1] = valid ? pkh(W_ih0[r * F + 2], W_ih0[r * F + 3]) : 0u;
  float b0 = valid ? (b_ih0[r] + b_hh0[r]) : 0.0f;
  float b1 = valid ? (b_ih1[r] + b_hh1[r]) : 0.0f;

#pragma unroll
  for (int k = 0; k < 5; ++k) { PIN(wh0p[k]); PIN(wi1p[k]); PIN(wh1p[k]); }
  PIN(wi0p[0]); PIN(wi0p[1]); PIN(b0); PIN(b1);

  const float4* __restrict__ xrow =
      reinterpret_cast<const float4*>(x + (size_t)e * (T * F));

  uint32_t h0p[5] = {0, 0, 0, 0, 0};   // packed h vectors (f16x2 pairs)
  uint32_t h1p[5] = {0, 0, 0, 0, 0};
  float acc = 0.0f;

  float4 x0 = xrow[0];
  uint32_t xpk0 = pkrtz(x0.x, x0.y), xpk1 = pkrtz(x0.z, x0.w);

#pragma unroll 1
  for (int t = 0; t < T; ++t) {
    float4 xn = xrow[(t + 1 < T) ? t + 1 : t];   // software prefetch
    float fw = s_wfc[t * HP + r];                // FC weight (pads read 0)

    // ---- layer 0 ----  (two chains s/p for ILP)
    float s = b0, p = 0.0f;
    mix2_lo(s, wi0p[0], xpk0); mix2_hi(s, wi0p[0], xpk0);
    mix2_lo(p, wi0p[1], xpk1); mix2_hi(p, wi0p[1], xpk1);
    mix2_lo(s, wh0p[0], h0p[0]); mix2_hi(s, wh0p[0], h0p[0]);
    mix2_lo(p, wh0p[1], h0p[1]); mix2_hi(p, wh0p[1], h0p[1]);
    mix2_lo(s, wh0p[2], h0p[2]); mix2_hi(s, wh0p[2], h0p[2]);
    mix2_lo(p, wh0p[3], h0p[3]); mix2_hi(p, wh0p[3], h0p[3]);
    mix2_lo(s, wh0p[4], h0p[4]); mix2_hi(s, wh0p[4], h0p[4]);
    float m = fast_tanh(s + p);   // pads: tanh(0) = 0 exactly

    // exchange: pack pair locally, broadcast 5 pairs to all 16 lanes
    {
      uint32_t pk = pkrtz(m, pairswap(m));  // even lanes 2k: (h_2k, h_2k+1)
      h0p[0] = swz16<0>(pk); h0p[1] = swz16<2>(pk); h0p[2] = swz16<4>(pk);
      h0p[3] = swz16<6>(pk); h0p[4] = swz16<8>(pk);
    }

    // ---- layer 1 ----
    s = b1; p = 0.0f;
    mix2_lo(s, wi1p[0], h0p[0]); mix2_hi(s, wi1p[0], h0p[0]);
    mix2_lo(p, wi1p[1], h0p[1]); mix2_hi(p, wi1p[1], h0p[1]);
    mix2_lo(s, wi1p[2], h0p[2]); mix2_hi(s, wi1p[2], h0p[2]);
    mix2_lo(p, wi1p[3], h0p[3]); mix2_hi(p, wi1p[3], h0p[3]);
    mix2_lo(s, wi1p[4], h0p[4]); mix2_hi(s, wi1p[4], h0p[4]);
    mix2_lo(p, wh1p[0], h1p[0]); mix2_hi(p, wh1p[0], h1p[0]);
    mix2_lo(s, wh1p[1], h1p[1]); mix2_hi(s, wh1p[1], h1p[1]);
    mix2_lo(p, wh1p[2], h1p[2]); mix2_hi(p, wh1p[2], h1p[2]);
    mix2_lo(s, wh1p[3], h1p[3]); mix2_hi(s, wh1p[3], h1p[3]);
    mix2_lo(p, wh1p[4], h1p[4]); mix2_hi(p, wh1p[4], h1p[4]);
    m = fast_tanh(s + p);

    acc = fmaf(m, fw, acc);

    {
      uint32_t pk = pkrtz(m, pairswap(m));
      h1p[0] = swz16<0>(pk); h1p[1] = swz16<2>(pk); h1p[2] = swz16<4>(pk);
      h1p[3] = swz16<6>(pk); h1p[4] = swz16<8>(pk);
    }

    xpk0 = pkrtz(xn.x, xn.y);
    xpk1 = pkrtz(xn.z, xn.w);
  }

  // reduce FC accumulator across the 16 lanes
  acc += __shfl_xor(acc, 1);
  acc += __shfl_xor(acc, 2);
  acc += __shfl_xor(acc, 4);
  acc += __shfl_xor(acc, 8);
  if (r == 0) out[e] = fast_sigmoid(acc + b_fc[0]);
}

}  // namespace

extern "C" void kernel_launch(void* const* d_in, const int* in_sizes, int n_in,
                              void* d_out, int out_size, void* d_ws, size_t ws_size,
                              hipStream_t stream) {
  const float* x     = (const float*)d_in[0];
  const float* W_ih0 = (const float*)d_in[1];
  const float* W_hh0 = (const float*)d_in[2];
  const float* b_ih0 = (const float*)d_in[3];
  const float* b_hh0 = (const float*)d_in[4];
  const float* W_ih1 = (const float*)d_in[5];
  const float* W_hh1 = (const float*)d_in[6];
  const float* b_ih1 = (const float*)d_in[7];
  const float* b_hh1 = (const float*)d_in[8];
  const float* W_fc  = (const float*)d_in[9];
  const float* b_fc  = (const float*)d_in[10];
  float* out = (float*)d_out;

  dim3 grid((Bsz * 16) / BLOCK), block(BLOCK);
  hipLaunchKernelGGL(rnn2_hex, grid, block, 0, stream,
                     x, W_ih0, W_hh0, b_ih0, b_hh0,
                     W_ih1, W_hh1, b_ih1, b_hh1, W_fc, b_fc, out);
}

// Round 10
// 117.682 us; speedup vs baseline: 1.1626x; 1.1626x over previous
//
#include <hip/hip_runtime.h>
#include <math.h>

namespace {

constexpr int Bsz   = 16384;
constexpr int T     = 200;
constexpr int F     = 4;
constexpr int H     = 10;
constexpr int HP    = 16;   // FC LDS padding: 16 slots/step
constexpr int BLOCK = 64;   // ONE wave per block: the only config where the
                            // allocator has ever granted >90 arch VGPRs (r3:
                            // 204). 256-thread blocks capped at 48-88 and
                            // parked the overflow in AGPRs -> v_accvgpr_read
                            // churn (~2x VALU inflation, rounds 5-9).

// tanh(x) = 1 - 2/(exp(2x)+1); saturates correctly to +/-1 for |x| large.
__device__ __forceinline__ float fast_tanh(float x) {
  float e = exp2f(x * 2.8853900817779268f);   // exp(2x) via v_exp_f32
  return 1.0f - 2.0f * __builtin_amdgcn_rcpf(e + 1.0f);
}

__device__ __forceinline__ float fast_sigmoid(float x) {
  float e = exp2f(x * -1.4426950408889634f);  // exp(-x)
  return __builtin_amdgcn_rcpf(1.0f + e);
}

// Broadcast sub-lane J's value to all lanes of each 8-lane group.
// ds_swizzle BitMode: new_lane = (lane & 0x18) | J.
template <int J>
__device__ __forceinline__ float bcast8(float v) {
  return __int_as_float(
      __builtin_amdgcn_ds_swizzle(__float_as_int(v), (J << 5) | 0x18));
}

// Prevent rematerialization of a loaded value inside the t-loop.
#define PIN(v) asm volatile("" : "+v"(v))

__global__ __launch_bounds__(BLOCK, 2) void rnn2_oct64(
    const float* __restrict__ x,
    const float* __restrict__ W_ih0, const float* __restrict__ W_hh0,
    const float* __restrict__ b_ih0, const float* __restrict__ b_hh0,
    const float* __restrict__ W_ih1, const float* __restrict__ W_hh1,
    const float* __restrict__ b_ih1, const float* __restrict__ b_hh1,
    const float* __restrict__ W_fc, const float* __restrict__ b_fc,
    float* __restrict__ out) {
  // FC weights in LDS, padded to HP floats per timestep (pad = 0).
  __shared__ float s_wfc[T * HP];
  for (int i = threadIdx.x; i < T * HP; i += BLOCK) {
    int t = i >> 4, u = i & 15;
    s_wfc[i] = (u < H) ? W_fc[t * H + u] : 0.0f;
  }
  __syncthreads();

  const int g  = blockIdx.x * BLOCK + threadIdx.x;
  const int b  = g >> 3;        // batch element
  const int r  = g & 7;         // sub-lane in 8-group
  const int uA = r;             // first unit  (always real: r <= 7 < 10)
  const int uB = 8 + r;         // second unit (real only for r < 2)
  const bool vB = (uB < H);

  // ---- my 2 units' weights, zero-padded, pinned into VGPRs (72 floats) ----
  float wi0A[F], wh0A[H], wi1A[H], wh1A[H];
  float wi0B[F], wh0B[H], wi1B[H], wh1B[H];
  float bA0, bA1, bB0, bB1;
#pragma unroll
  for (int j = 0; j < F; ++j) {
    wi0A[j] = W_ih0[uA * F + j];              PIN(wi0A[j]);
    wi0B[j] = vB ? W_ih0[uB * F + j] : 0.0f;  PIN(wi0B[j]);
  }
#pragma unroll
  for (int j = 0; j < H; ++j) {
    wh0A[j] = W_hh0[uA * H + j];              PIN(wh0A[j]);
    wh0B[j] = vB ? W_hh0[uB * H + j] : 0.0f;  PIN(wh0B[j]);
    wi1A[j] = W_ih1[uA * H + j];              PIN(wi1A[j]);
    wi1B[j] = vB ? W_ih1[uB * H + j] : 0.0f;  PIN(wi1B[j]);
    wh1A[j] = W_hh1[uA * H + j];              PIN(wh1A[j]);
    wh1B[j] = vB ? W_hh1[uB * H + j] : 0.0f;  PIN(wh1B[j]);
  }
  bA0 = b_ih0[uA] + b_hh0[uA];               PIN(bA0);
  bB0 = vB ? (b_ih0[uB] + b_hh0[uB]) : 0.0f; PIN(bB0);
  bA1 = b_ih1[uA] + b_hh1[uA];               PIN(bA1);
  bB1 = vB ? (b_ih1[uB] + b_hh1[uB]) : 0.0f; PIN(bB1);

  const float4* __restrict__ xrow =
      reinterpret_cast<const float4*>(x + (size_t)b * (T * F));

  float h0b[H], h1b[H];   // full broadcast h-vectors (units 0..9)
#pragma unroll
  for (int j = 0; j < H; ++j) { h0b[j] = 0.0f; h1b[j] = 0.0f; }
  float acc = 0.0f;

  float4 xv = xrow[0];
#pragma unroll 1
  for (int t = 0; t < T; ++t) {
    float4 xn = (t + 1 < T) ? xrow[t + 1] : xv;  // software prefetch

    // FC weights for this step — issued ~200 cycles before use.
    float fA = s_wfc[t * HP + uA];
    float fB = s_wfc[t * HP + uB];

    // ---- layer 0, my 2 units ----
    float sA = bA0, sB = bB0;
    sA = fmaf(wi0A[0], xv.x, sA);  sB = fmaf(wi0B[0], xv.x, sB);
    sA = fmaf(wi0A[1], xv.y, sA);  sB = fmaf(wi0B[1], xv.y, sB);
    sA = fmaf(wi0A[2], xv.z, sA);  sB = fmaf(wi0B[2], xv.z, sB);
    sA = fmaf(wi0A[3], xv.w, sA);  sB = fmaf(wi0B[3], xv.w, sB);
#pragma unroll
    for (int j = 0; j < H; ++j) {
      sA = fmaf(wh0A[j], h0b[j], sA);
      sB = fmaf(wh0B[j], h0b[j], sB);
    }
    float mA = fast_tanh(sA), mB = fast_tanh(sB);

    // layer 1's h1-recurrent half FIRST: independent of the h0 exchange, so
    // the scheduler has 20 FMAs to issue while the swizzles are in flight.
    float pA = bA1, pB = bB1;
#pragma unroll
    for (int j = 0; j < H; ++j) {
      pA = fmaf(wh1A[j], h1b[j], pA);
      pB = fmaf(wh1B[j], h1b[j], pB);
    }

    // broadcast new h0 across the 8-group: units 0..7 live in mA, 8..9 in mB
    h0b[0] = bcast8<0>(mA); h0b[1] = bcast8<1>(mA);
    h0b[2] = bcast8<2>(mA); h0b[3] = bcast8<3>(mA);
    h0b[4] = bcast8<4>(mA); h0b[5] = bcast8<5>(mA);
    h0b[6] = bcast8<6>(mA); h0b[7] = bcast8<7>(mA);
    h0b[8] = bcast8<0>(mB); h0b[9] = bcast8<1>(mB);

    // ---- layer 1, h0-dependent half ----
#pragma unroll
    for (int j = 0; j < H; ++j) {
      pA = fmaf(wi1A[j], h0b[j], pA);
      pB = fmaf(wi1B[j], h0b[j], pB);
    }
    mA = fast_tanh(pA); mB = fast_tanh(pB);

    // FC head contribution (pad units read 0 weights from LDS)
    acc = fmaf(mA, fA, acc);
    acc = fmaf(mB, fB, acc);

    // broadcast new h1 across the 8-group
    h1b[0] = bcast8<0>(mA); h1b[1] = bcast8<1>(mA);
    h1b[2] = bcast8<2>(mA); h1b[3] = bcast8<3>(mA);
    h1b[4] = bcast8<4>(mA); h1b[5] = bcast8<5>(mA);
    h1b[6] = bcast8<6>(mA); h1b[7] = bcast8<7>(mA);
    h1b[8] = bcast8<0>(mB); h1b[9] = bcast8<1>(mB);

    xv = xn;
  }

  // 8-lane reduce of the FC accumulator
  acc += __shfl_xor(acc, 1);
  acc += __shfl_xor(acc, 2);
  acc += __shfl_xor(acc, 4);
  if (r == 0) out[b] = fast_sigmoid(acc + b_fc[0]);
}

}  // namespace

extern "C" void kernel_launch(void* const* d_in, const int* in_sizes, int n_in,
                              void* d_out, int out_size, void* d_ws, size_t ws_size,
                              hipStream_t stream) {
  const float* x     = (const float*)d_in[0];
  const float* W_ih0 = (const float*)d_in[1];
  const float* W_hh0 = (const float*)d_in[2];
  const float* b_ih0 = (const float*)d_in[3];
  const float* b_hh0 = (const float*)d_in[4];
  const float* W_ih1 = (const float*)d_in[5];
  const float* W_hh1 = (const float*)d_in[6];
  const float* b_ih1 = (const float*)d_in[7];
  const float* b_hh1 = (const float*)d_in[8];
  const float* W_fc  = (const float*)d_in[9];
  const float* b_fc  = (const float*)d_in[10];
  float* out = (float*)d_out;

  dim3 grid((Bsz * 8) / BLOCK), block(BLOCK);
  hipLaunchKernelGGL(rnn2_oct64, grid, block, 0, stream,
                     x, W_ih0, W_hh0, b_ih0, b_hh0,
                     W_ih1, W_hh1, b_ih1, b_hh1, W_fc, b_fc, out);
}